// Round 3
// baseline (605.545 us; speedup 1.0000x reference)
//
#include <hip/hip_runtime.h>
#include <hip/hip_bf16.h>
#include <stdint.h>

#define N_EXPERTS 8
#define D_MODEL   1024
#define D_FF      4096
#define T_TOKENS  2048
#define MT        128     // M-tile both GEMMs
#define MAXT      24      // sum ceil(c/128) <= 2048/128 + 8
#define KSPLIT    4       // gemm2 K-split (4096/4 = 1024 per block, 16 iters)

typedef __attribute__((ext_vector_type(8))) short bf16x8;
typedef __attribute__((ext_vector_type(4))) float f32x4;

// workspace byte offsets
#define XG_OFF   (16384)
#define H_OFF    (16384 + 4u*1024*1024)
#define WG_OFF   (32u*1024*1024)
#define WU_OFF   (96u*1024*1024)
#define WD_OFF   (160u*1024*1024)

__device__ __forceinline__ unsigned short f2bfu(float f) {
    union { float f; uint32_t u; } v; v.f = f;
    uint32_t u = v.u;
    return (unsigned short)((u + 0x7fffu + ((u >> 16) & 1u)) >> 16);
}

__device__ __forceinline__ short f2bf(float f) { return (short)f2bfu(f); }

__device__ __forceinline__ uint32_t pack2bf(float a, float b) {
    __hip_bfloat162 h = __float22bfloat162_rn(make_float2(a, b));
    return *(uint32_t*)&h;
}

// async global->LDS, 16B per lane; lds dst must be wave-uniform base (+ lane*16 implicit)
__device__ __forceinline__ void gl_lds16(const short* g, short* l) {
    __builtin_amdgcn_global_load_lds(
        (const __attribute__((address_space(1))) unsigned int*)(g),
        (__attribute__((address_space(3))) unsigned int*)(l), 16, 0, 0);
}

// ---------------- routing: count + scan + MT=128 tile table ----------------

__global__ void moe_route(const int* __restrict__ idx, int* __restrict__ offsets,
                          int* __restrict__ ntp, int* __restrict__ t_e,
                          int* __restrict__ t_p0, int* __restrict__ t_end) {
    __shared__ int cnt[N_EXPERTS];
    int tid = threadIdx.x;
    if (tid < N_EXPERTS) cnt[tid] = 0;
    __syncthreads();
    for (int t = tid; t < T_TOKENS; t += 256) atomicAdd(&cnt[idx[t]], 1);
    __syncthreads();
    if (tid == 0) {
        int off = 0, nt = 0;
        for (int e = 0; e < N_EXPERTS; ++e) {
            offsets[e] = off;
            int c = cnt[e], end = off + c;
            for (int i = 0; i < c; i += MT) { t_e[nt] = e; t_p0[nt] = off + i; t_end[nt] = end; ++nt; }
            off = end;
        }
        offsets[N_EXPERTS] = off;
        *ntp = nt;
    }
}

// one block per token: claim a permuted row slot, gather+convert x row to bf16
__global__ void moe_gather(const float* __restrict__ x, const int* __restrict__ idx,
                           const int* __restrict__ offsets, int* __restrict__ cursor,
                           int* __restrict__ tok_of_row, short* __restrict__ Xg) {
    __shared__ int sp;
    int t = blockIdx.x;
    if (threadIdx.x == 0) {
        int e = idx[t];
        int p = offsets[e] + atomicAdd(&cursor[e], 1);
        tok_of_row[p] = t;
        sp = p;
    }
    __syncthreads();
    int p = sp;
    const float4* src = (const float4*)(x + (size_t)t * D_MODEL);
    uint2* dst = (uint2*)(Xg + (size_t)p * D_MODEL);
    int i = threadIdx.x;
    float4 v = src[i];
    uint2 o;
    o.x = pack2bf(v.x, v.y);
    o.y = pack2bf(v.z, v.w);
    dst[i] = o;
}

// ---------------- weight repack: fp32 [e][K][N] -> bf16 tiles ----------------
// dst layout: [e][nt(N/64)][ks(K/64)] slabs of 4096 shorts; within a slab,
// logical (n,k) lives at short offset n*64 + ((k>>3 ^ (n&7))*8 + (k&7))
// (the XOR bakes the T2 bank-swizzle so GEMM can global_load_lds linearly).
// Per block: (nslab 256 cols, kslab 64 rows, e). Contiguous row reads,
// LDS transpose, contiguous tile writes.

__launch_bounds__(256)
__global__ void moe_repack(const float* __restrict__ src, short* __restrict__ dst,
                           int K, int N) {
    __shared__ short Lt[256][72];   // [n_local][k_local(64) padded], col-swizzled

    int e = blockIdx.z, kslab = blockIdx.y, nslab = blockIdx.x;
    int NT = N >> 6, KS = K >> 6;
    int tid = threadIdx.x;
    int w = tid >> 6, l = tid & 63;

    const float* sb = src + ((size_t)e * K + (size_t)kslab * 64) * N
                      + (size_t)nslab * 256 + 4 * l;

#pragma unroll
    for (int g = 0; g < 4; ++g) {
        int r0 = g * 16 + w * 4;
        float4 v0 = *(const float4*)(sb + (size_t)(r0    ) * N);
        float4 v1 = *(const float4*)(sb + (size_t)(r0 + 1) * N);
        float4 v2 = *(const float4*)(sb + (size_t)(r0 + 2) * N);
        float4 v3 = *(const float4*)(sb + (size_t)(r0 + 3) * N);
        // transpose 4 rows x 4 cols -> 4 column-vectors along k
        {
            int n = 4 * l + 0; int cc = r0 ^ (((n >> 3) & 3) << 3);
            ushort4 tv = { f2bfu(v0.x), f2bfu(v1.x), f2bfu(v2.x), f2bfu(v3.x) };
            *(ushort4*)&Lt[n][cc] = tv;
        }
        {
            int n = 4 * l + 1; int cc = r0 ^ (((n >> 3) & 3) << 3);
            ushort4 tv = { f2bfu(v0.y), f2bfu(v1.y), f2bfu(v2.y), f2bfu(v3.y) };
            *(ushort4*)&Lt[n][cc] = tv;
        }
        {
            int n = 4 * l + 2; int cc = r0 ^ (((n >> 3) & 3) << 3);
            ushort4 tv = { f2bfu(v0.z), f2bfu(v1.z), f2bfu(v2.z), f2bfu(v3.z) };
            *(ushort4*)&Lt[n][cc] = tv;
        }
        {
            int n = 4 * l + 3; int cc = r0 ^ (((n >> 3) & 3) << 3);
            ushort4 tv = { f2bfu(v0.w), f2bfu(v1.w), f2bfu(v2.w), f2bfu(v3.w) };
            *(ushort4*)&Lt[n][cc] = tv;
        }
    }
    __syncthreads();

    int t = tid >> 6, idx = tid & 63;
#pragma unroll
    for (int i = 0; i < 8; ++i) {
        int u = i * 64 + idx;
        int n = u >> 3, k8 = u & 7;
        int sw = ((n >> 3) & 3) << 3;
        bf16x8 vv = *(const bf16x8*)&Lt[t * 64 + n][(k8 * 8) ^ sw];
        size_t tb = (((size_t)e * NT + (size_t)nslab * 4 + t) * KS + kslab) * 4096;
        *(bf16x8*)&dst[tb + n * 64 + ((k8 ^ (n & 7)) * 8)] = vv;
    }
}

// ---------------- GEMM1: gate/up + SwiGLU -> h (bf16) ----------------
// grid (64 n-tiles, MAXT), block 256 (4 waves). M=128 N=64 BK=64.
// B staged via global_load_lds from contiguous repacked slabs (swizzle baked).

__launch_bounds__(256)
__global__ void moe_gemm1(const short* __restrict__ wgt, const short* __restrict__ wut,
                          const short* __restrict__ Xg, short* __restrict__ h,
                          const int* __restrict__ t_e, const int* __restrict__ t_p0,
                          const int* __restrict__ t_end, const int* __restrict__ ntp) {
    int ti = blockIdx.y;
    if (ti >= *ntp) return;
    int e = t_e[ti], p0 = t_p0[ti], pend = t_end[ti];
    int nt = blockIdx.x;

    __shared__ short Bg[2][4096];
    __shared__ short Bu[2][4096];

    int tid = threadIdx.x;
    int lane = tid & 63, w = tid >> 6;
    int col = lane & 15, quad = lane >> 4;

    const short* gsrc = wgt + ((size_t)e * 64 + nt) * 16 * 4096 + w * 1024 + lane * 8;
    const short* usrc = wut + ((size_t)e * 64 + nt) * 16 * 4096 + w * 1024 + lane * 8;

    int row0 = p0 + w * 32 + col;  if (row0 > T_TOKENS - 1) row0 = T_TOKENS - 1;
    int row1 = row0 + 16;          if (row1 > T_TOKENS - 1) row1 = T_TOKENS - 1;
    const short* a0p = Xg + (size_t)row0 * D_MODEL + quad * 8;
    const short* a1p = Xg + (size_t)row1 * D_MODEL + quad * 8;

    int boff0[4], boff1[4];
#pragma unroll
    for (int nf = 0; nf < 4; ++nf) {
        int n = nf * 16 + col;
        boff0[nf] = n * 64 + ((quad ^ (n & 7)) * 8);
        boff1[nf] = n * 64 + (((quad + 4) ^ (n & 7)) * 8);
    }

    f32x4 accg[2][4], accu[2][4];
#pragma unroll
    for (int m = 0; m < 2; ++m)
#pragma unroll
        for (int nf = 0; nf < 4; ++nf) {
            accg[m][nf] = (f32x4){0,0,0,0};
            accu[m][nf] = (f32x4){0,0,0,0};
        }

    // prologue: stage slab 0
    gl_lds16(gsrc,       &Bg[0][w * 1024]);
    gl_lds16(gsrc + 512, &Bg[0][w * 1024 + 512]);
    gl_lds16(usrc,       &Bu[0][w * 1024]);
    gl_lds16(usrc + 512, &Bu[0][w * 1024 + 512]);
    bf16x8 a00 = *(const bf16x8*)(a0p);
    bf16x8 a01 = *(const bf16x8*)(a0p + 32);
    bf16x8 a10 = *(const bf16x8*)(a1p);
    bf16x8 a11 = *(const bf16x8*)(a1p + 32);
    __syncthreads();

    int p = 0;
#pragma unroll 1
    for (int it = 0; it < 16; ++it) {
        int itn = (it + 1) & 15;                 // wrapped prefetch on last iter
        const short* gs = gsrc + (size_t)itn * 4096;
        const short* us = usrc + (size_t)itn * 4096;
        gl_lds16(gs,       &Bg[p ^ 1][w * 1024]);
        gl_lds16(gs + 512, &Bg[p ^ 1][w * 1024 + 512]);
        gl_lds16(us,       &Bu[p ^ 1][w * 1024]);
        gl_lds16(us + 512, &Bu[p ^ 1][w * 1024 + 512]);
        int kn = itn * 64;
        bf16x8 a00n = *(const bf16x8*)(a0p + kn);
        bf16x8 a01n = *(const bf16x8*)(a0p + kn + 32);
        bf16x8 a10n = *(const bf16x8*)(a1p + kn);
        bf16x8 a11n = *(const bf16x8*)(a1p + kn + 32);

#pragma unroll
        for (int nf = 0; nf < 4; ++nf) {
            bf16x8 bg0 = *(const bf16x8*)&Bg[p][boff0[nf]];
            bf16x8 bg1 = *(const bf16x8*)&Bg[p][boff1[nf]];
            bf16x8 bu0 = *(const bf16x8*)&Bu[p][boff0[nf]];
            bf16x8 bu1 = *(const bf16x8*)&Bu[p][boff1[nf]];
            accg[0][nf] = __builtin_amdgcn_mfma_f32_16x16x32_bf16(a00, bg0, accg[0][nf], 0, 0, 0);
            accg[0][nf] = __builtin_amdgcn_mfma_f32_16x16x32_bf16(a01, bg1, accg[0][nf], 0, 0, 0);
            accg[1][nf] = __builtin_amdgcn_mfma_f32_16x16x32_bf16(a10, bg0, accg[1][nf], 0, 0, 0);
            accg[1][nf] = __builtin_amdgcn_mfma_f32_16x16x32_bf16(a11, bg1, accg[1][nf], 0, 0, 0);
            accu[0][nf] = __builtin_amdgcn_mfma_f32_16x16x32_bf16(a00, bu0, accu[0][nf], 0, 0, 0);
            accu[0][nf] = __builtin_amdgcn_mfma_f32_16x16x32_bf16(a01, bu1, accu[0][nf], 0, 0, 0);
            accu[1][nf] = __builtin_amdgcn_mfma_f32_16x16x32_bf16(a10, bu0, accu[1][nf], 0, 0, 0);
            accu[1][nf] = __builtin_amdgcn_mfma_f32_16x16x32_bf16(a11, bu1, accu[1][nf], 0, 0, 0);
        }

        a00 = a00n; a01 = a01n; a10 = a10n; a11 = a11n;
        __syncthreads();                         // drains vmcnt -> buf p^1 ready
        p ^= 1;
    }

    // epilogue: h = silu(gate) * up, masked rows
#pragma unroll
    for (int m = 0; m < 2; ++m) {
#pragma unroll
        for (int r = 0; r < 4; ++r) {
            int mr = p0 + w * 32 + m * 16 + quad * 4 + r;
            if (mr < pend) {
#pragma unroll
                for (int nf = 0; nf < 4; ++nf) {
                    float gv = accg[m][nf][r], uv = accu[m][nf][r];
                    float hv = (gv / (1.f + __expf(-gv))) * uv;
                    h[(size_t)mr * D_FF + nt * 64 + nf * 16 + col] = f2bf(hv);
                }
            }
        }
    }
}

// ---------------- GEMM2: out += h @ Wd (K-split x4), scatter via atomics ----------------
// grid (16 d-tiles, MAXT, KSPLIT), block 256. M=128 N=64 BK=64, 16 iters.

__launch_bounds__(256)
__global__ void moe_gemm2(const short* __restrict__ wdt, const short* __restrict__ h,
                          const int* __restrict__ tok_of_row, float* __restrict__ out,
                          const int* __restrict__ t_e, const int* __restrict__ t_p0,
                          const int* __restrict__ t_end, const int* __restrict__ ntp) {
    int ti = blockIdx.y;
    if (ti >= *ntp) return;
    int e = t_e[ti], p0 = t_p0[ti], pend = t_end[ti];
    int dt = blockIdx.x, z = blockIdx.z;

    __shared__ short Bd[2][4096];

    int tid = threadIdx.x;
    int lane = tid & 63, w = tid >> 6;
    int col = lane & 15, quad = lane >> 4;

    const short* dsrc = wdt + (((size_t)e * 16 + dt) * 64 + z * 16) * 4096 + w * 1024 + lane * 8;
    int Koff = z * (D_FF / KSPLIT);

    int row0 = p0 + w * 32 + col;  if (row0 > T_TOKENS - 1) row0 = T_TOKENS - 1;
    int row1 = row0 + 16;          if (row1 > T_TOKENS - 1) row1 = T_TOKENS - 1;
    const short* a0p = h + (size_t)row0 * D_FF + Koff + quad * 8;
    const short* a1p = h + (size_t)row1 * D_FF + Koff + quad * 8;

    int boff0[4], boff1[4];
#pragma unroll
    for (int nf = 0; nf < 4; ++nf) {
        int n = nf * 16 + col;
        boff0[nf] = n * 64 + ((quad ^ (n & 7)) * 8);
        boff1[nf] = n * 64 + (((quad + 4) ^ (n & 7)) * 8);
    }

    f32x4 acc[2][4];
#pragma unroll
    for (int m = 0; m < 2; ++m)
#pragma unroll
        for (int nf = 0; nf < 4; ++nf) acc[m][nf] = (f32x4){0,0,0,0};

    gl_lds16(dsrc,       &Bd[0][w * 1024]);
    gl_lds16(dsrc + 512, &Bd[0][w * 1024 + 512]);
    bf16x8 a00 = *(const bf16x8*)(a0p);
    bf16x8 a01 = *(const bf16x8*)(a0p + 32);
    bf16x8 a10 = *(const bf16x8*)(a1p);
    bf16x8 a11 = *(const bf16x8*)(a1p + 32);
    __syncthreads();

    int p = 0;
#pragma unroll 1
    for (int it = 0; it < 16; ++it) {
        int itn = (it + 1) & 15;
        const short* ds = dsrc + (size_t)itn * 4096;
        gl_lds16(ds,       &Bd[p ^ 1][w * 1024]);
        gl_lds16(ds + 512, &Bd[p ^ 1][w * 1024 + 512]);
        int kn = itn * 64;
        bf16x8 a00n = *(const bf16x8*)(a0p + kn);
        bf16x8 a01n = *(const bf16x8*)(a0p + kn + 32);
        bf16x8 a10n = *(const bf16x8*)(a1p + kn);
        bf16x8 a11n = *(const bf16x8*)(a1p + kn + 32);

#pragma unroll
        for (int nf = 0; nf < 4; ++nf) {
            bf16x8 b0 = *(const bf16x8*)&Bd[p][boff0[nf]];
            bf16x8 b1 = *(const bf16x8*)&Bd[p][boff1[nf]];
            acc[0][nf] = __builtin_amdgcn_mfma_f32_16x16x32_bf16(a00, b0, acc[0][nf], 0, 0, 0);
            acc[0][nf] = __builtin_amdgcn_mfma_f32_16x16x32_bf16(a01, b1, acc[0][nf], 0, 0, 0);
            acc[1][nf] = __builtin_amdgcn_mfma_f32_16x16x32_bf16(a10, b0, acc[1][nf], 0, 0, 0);
            acc[1][nf] = __builtin_amdgcn_mfma_f32_16x16x32_bf16(a11, b1, acc[1][nf], 0, 0, 0);
        }

        a00 = a00n; a01 = a01n; a10 = a10n; a11 = a11n;
        __syncthreads();
        p ^= 1;
    }

#pragma unroll
    for (int m = 0; m < 2; ++m) {
#pragma unroll
        for (int r = 0; r < 4; ++r) {
            int mr = p0 + w * 32 + m * 16 + quad * 4 + r;
            if (mr < pend) {
                int t = tok_of_row[mr];
#pragma unroll
                for (int nf = 0; nf < 4; ++nf)
                    atomicAdd(&out[(size_t)t * D_MODEL + dt * 64 + nf * 16 + col], acc[m][nf][r]);
            }
        }
    }
}

// ---------------- launch ----------------

extern "C" void kernel_launch(void* const* d_in, const int* in_sizes, int n_in,
                              void* d_out, int out_size, void* d_ws, size_t ws_size,
                              hipStream_t stream) {
    (void)in_sizes; (void)n_in; (void)out_size; (void)ws_size;
    const float* x   = (const float*)d_in[0];
    const int*   idx = (const int*)d_in[1];
    const float* wg  = (const float*)d_in[2];
    const float* wu  = (const float*)d_in[3];
    const float* wd  = (const float*)d_in[4];
    float* out = (float*)d_out;

    int* ws_i       = (int*)d_ws;
    int* cursor     = ws_i;            // 8   (memset to 0)
    int* offsets    = ws_i + 8;        // 9
    int* nt         = ws_i + 20;       // 1
    int* t_e        = ws_i + 32;       // 24
    int* t_p0       = ws_i + 64;       // 24
    int* t_end      = ws_i + 96;       // 24
    int* tok_of_row = ws_i + 256;      // 2048

    short* Xg  = (short*)((char*)d_ws + XG_OFF);
    short* h   = (short*)((char*)d_ws + H_OFF);
    short* WGt = (short*)((char*)d_ws + WG_OFF);
    short* WUt = (short*)((char*)d_ws + WU_OFF);
    short* WDt = (short*)((char*)d_ws + WD_OFF);

    hipMemsetAsync(d_ws, 0, 128, stream);
    hipMemsetAsync(out, 0, (size_t)T_TOKENS * D_MODEL * sizeof(float), stream);
    moe_route<<<dim3(1), 256, 0, stream>>>(idx, offsets, nt, t_e, t_p0, t_end);
    moe_gather<<<dim3(T_TOKENS), 256, 0, stream>>>(x, idx, offsets, cursor, tok_of_row, Xg);
    moe_repack<<<dim3(D_FF / 256, D_MODEL / 64, N_EXPERTS), 256, 0, stream>>>(wg, WGt, D_MODEL, D_FF);
    moe_repack<<<dim3(D_FF / 256, D_MODEL / 64, N_EXPERTS), 256, 0, stream>>>(wu, WUt, D_MODEL, D_FF);
    moe_repack<<<dim3(D_MODEL / 256, D_FF / 64, N_EXPERTS), 256, 0, stream>>>(wd, WDt, D_FF, D_MODEL);
    moe_gemm1<<<dim3(D_FF / 64, MAXT), 256, 0, stream>>>(WGt, WUt, Xg, h,
                                                         t_e, t_p0, t_end, nt);
    moe_gemm2<<<dim3(D_MODEL / 64, MAXT, KSPLIT), 256, 0, stream>>>(WDt, h, tok_of_row, out,
                                                                    t_e, t_p0, t_end, nt);
}

// Round 5
// 566.709 us; speedup vs baseline: 1.0685x; 1.0685x over previous
//
#include <hip/hip_runtime.h>
#include <hip/hip_bf16.h>
#include <stdint.h>

#define N_EXPERTS 8
#define D_MODEL   1024
#define D_FF      4096
#define T_TOKENS  2048
#define MT        128     // M-tile both GEMMs
#define MAXT      24      // sum ceil(c/128) <= 2048/128 + 8
#define KSPLIT    4       // gemm2 K-split (4096/4 = 1024 per block, 16 iters)

typedef __attribute__((ext_vector_type(8))) short bf16x8;
typedef __attribute__((ext_vector_type(4))) float f32x4;

// workspace byte offsets
#define XG_OFF   (16384)
#define H_OFF    (16384 + 4u*1024*1024)
#define WG_OFF   (32u*1024*1024)
#define WU_OFF   (96u*1024*1024)
#define WD_OFF   (160u*1024*1024)

__device__ __forceinline__ unsigned short f2bfu(float f) {
    union { float f; uint32_t u; } v; v.f = f;
    uint32_t u = v.u;
    return (unsigned short)((u + 0x7fffu + ((u >> 16) & 1u)) >> 16);
}

__device__ __forceinline__ short f2bf(float f) { return (short)f2bfu(f); }

__device__ __forceinline__ uint32_t pack2bf(float a, float b) {
    __hip_bfloat162 h = __float22bfloat162_rn(make_float2(a, b));
    return *(uint32_t*)&h;
}

// async global->LDS, 16B per lane; lds dst is wave-uniform base (+ lane*16 implicit)
__device__ __forceinline__ void gl_lds16(const short* g, short* l) {
    __builtin_amdgcn_global_load_lds(
        (const __attribute__((address_space(1))) unsigned int*)(g),
        (__attribute__((address_space(3))) unsigned int*)(l), 16, 0, 0);
}

// counted-vmcnt barrier: keep N newest VMEM ops in flight, drain LDS, sync.
#define PIPE_BARRIER(N)                                              \
    asm volatile("s_waitcnt vmcnt(" #N ") lgkmcnt(0)" ::: "memory"); \
    __builtin_amdgcn_sched_barrier(0);                               \
    __builtin_amdgcn_s_barrier();                                    \
    __builtin_amdgcn_sched_barrier(0);

// ---------------- routing: count + scan + MT=128 tile table ----------------

__global__ void moe_route(const int* __restrict__ idx, int* __restrict__ offsets,
                          int* __restrict__ ntp, int* __restrict__ t_e,
                          int* __restrict__ t_p0, int* __restrict__ t_end) {
    __shared__ int cnt[N_EXPERTS];
    int tid = threadIdx.x;
    if (tid < N_EXPERTS) cnt[tid] = 0;
    __syncthreads();
    for (int t = tid; t < T_TOKENS; t += 256) atomicAdd(&cnt[idx[t]], 1);
    __syncthreads();
    if (tid == 0) {
        int off = 0, nt = 0;
        for (int e = 0; e < N_EXPERTS; ++e) {
            offsets[e] = off;
            int c = cnt[e], end = off + c;
            for (int i = 0; i < c; i += MT) { t_e[nt] = e; t_p0[nt] = off + i; t_end[nt] = end; ++nt; }
            off = end;
        }
        offsets[N_EXPERTS] = off;
        *ntp = nt;
    }
}

// one block per token: claim a permuted row slot, gather+convert x row to bf16
__global__ void moe_gather(const float* __restrict__ x, const int* __restrict__ idx,
                           const int* __restrict__ offsets, int* __restrict__ cursor,
                           int* __restrict__ tok_of_row, short* __restrict__ Xg) {
    __shared__ int sp;
    int t = blockIdx.x;
    if (threadIdx.x == 0) {
        int e = idx[t];
        int p = offsets[e] + atomicAdd(&cursor[e], 1);
        tok_of_row[p] = t;
        sp = p;
    }
    __syncthreads();
    int p = sp;
    const float4* src = (const float4*)(x + (size_t)t * D_MODEL);
    uint2* dst = (uint2*)(Xg + (size_t)p * D_MODEL);
    int i = threadIdx.x;
    float4 v = src[i];
    uint2 o;
    o.x = pack2bf(v.x, v.y);
    o.y = pack2bf(v.z, v.w);
    dst[i] = o;
}

// ---------------- weight repack: fp32 [e][K][N] -> bf16 swizzled tiles ----------------
// Block = [64 k-rows x 512 n-cols]: reads are 2KB-contiguous row spans (k-slab rows
// are ADJACENT in memory), writes are 8KB-contiguous tiles. 512 threads.
// dst (n,k) in tile: short offset n*64 + ((k>>3 ^ (n&7))*8) + (k&7)  (T2 swizzle baked).

__launch_bounds__(512)
__global__ void moe_repack(const float* __restrict__ src, short* __restrict__ dst,
                           int K, int N) {
    __shared__ short Lt[512][72];

    int e = blockIdx.z, ks = blockIdx.y, nc = blockIdx.x;
    int NT = N >> 6, KS = K >> 6;
    int tid = threadIdx.x;
    int w = tid >> 6, l = tid & 63;

    // wave w handles rows w*8 .. w*8+7 of the k-slab
    const float* sb = src + ((size_t)e * K + (size_t)ks * 64 + w * 8) * N + (size_t)nc * 512;

#pragma unroll
    for (int q = 0; q < 2; ++q) {                // row-quad (4 rows)
        int r0 = w * 8 + q * 4;
#pragma unroll
        for (int hc = 0; hc < 2; ++hc) {         // column half (256 each)
            int c = 4 * l + hc * 256;
            float4 v0 = *(const float4*)(sb + ((size_t)(q * 4 + 0)) * N + c);
            float4 v1 = *(const float4*)(sb + ((size_t)(q * 4 + 1)) * N + c);
            float4 v2 = *(const float4*)(sb + ((size_t)(q * 4 + 2)) * N + c);
            float4 v3 = *(const float4*)(sb + ((size_t)(q * 4 + 3)) * N + c);
            {
                int n = c + 0; int cc = r0 ^ (((n >> 3) & 3) << 3);
                ushort4 tv = { f2bfu(v0.x), f2bfu(v1.x), f2bfu(v2.x), f2bfu(v3.x) };
                *(ushort4*)&Lt[n][cc] = tv;
            }
            {
                int n = c + 1; int cc = r0 ^ (((n >> 3) & 3) << 3);
                ushort4 tv = { f2bfu(v0.y), f2bfu(v1.y), f2bfu(v2.y), f2bfu(v3.y) };
                *(ushort4*)&Lt[n][cc] = tv;
            }
            {
                int n = c + 2; int cc = r0 ^ (((n >> 3) & 3) << 3);
                ushort4 tv = { f2bfu(v0.z), f2bfu(v1.z), f2bfu(v2.z), f2bfu(v3.z) };
                *(ushort4*)&Lt[n][cc] = tv;
            }
            {
                int n = c + 3; int cc = r0 ^ (((n >> 3) & 3) << 3);
                ushort4 tv = { f2bfu(v0.w), f2bfu(v1.w), f2bfu(v2.w), f2bfu(v3.w) };
                *(ushort4*)&Lt[n][cc] = tv;
            }
        }
    }
    __syncthreads();

    // wave t writes tile t (of 8): 8KB contiguous
    int t = w;
    size_t tb = (((size_t)e * NT + (size_t)nc * 8 + t) * KS + ks) * 4096;
#pragma unroll
    for (int i = 0; i < 8; ++i) {
        int u = i * 64 + l;
        int n = u >> 3, k8 = u & 7;
        int sw = ((n >> 3) & 3) << 3;
        bf16x8 vv = *(const bf16x8*)&Lt[t * 64 + n][(k8 * 8) ^ sw];
        *(bf16x8*)&dst[tb + n * 64 + ((k8 ^ (n & 7)) * 8)] = vv;
    }
}

// ---------------- GEMM1: gate/up + SwiGLU -> h (bf16) ----------------
// grid (64 n-tiles, MAXT), block 256 (4 waves). M=128 N=64 BK=64, 16 iters.
// 3-deep LDS pipeline, counted vmcnt: stage(i+2) in flight across barriers.
// Tail: at it==14 only stage(15)+A(15)=8 ops outstanding -> vmcnt(4) drains
// stage(15) into LDS before iteration 15 reads it (round-4 race fix).

__launch_bounds__(256)
__global__ void moe_gemm1(const short* __restrict__ wgt, const short* __restrict__ wut,
                          const short* __restrict__ Xg, short* __restrict__ h,
                          const int* __restrict__ t_e, const int* __restrict__ t_p0,
                          const int* __restrict__ t_end, const int* __restrict__ ntp) {
    int ti = blockIdx.y;
    if (ti >= *ntp) return;
    int e = t_e[ti], p0 = t_p0[ti], pend = t_end[ti];
    int nt = blockIdx.x;

    __shared__ short Bg[3][4096];
    __shared__ short Bu[3][4096];

    int tid = threadIdx.x;
    int lane = tid & 63, w = tid >> 6;
    int col = lane & 15, quad = lane >> 4;

    const short* gsrc = wgt + ((size_t)e * 64 + nt) * 16 * 4096 + w * 1024 + lane * 8;
    const short* usrc = wut + ((size_t)e * 64 + nt) * 16 * 4096 + w * 1024 + lane * 8;

    int row0 = p0 + w * 32 + col;  if (row0 > T_TOKENS - 1) row0 = T_TOKENS - 1;
    int row1 = row0 + 16;          if (row1 > T_TOKENS - 1) row1 = T_TOKENS - 1;
    const short* a0p = Xg + (size_t)row0 * D_MODEL + quad * 8;
    const short* a1p = Xg + (size_t)row1 * D_MODEL + quad * 8;

    int boff0[4], boff1[4];
#pragma unroll
    for (int nf = 0; nf < 4; ++nf) {
        int n = nf * 16 + col;
        boff0[nf] = n * 64 + ((quad ^ (n & 7)) * 8);
        boff1[nf] = n * 64 + (((quad + 4) ^ (n & 7)) * 8);
    }

    f32x4 accg[2][4], accu[2][4];
#pragma unroll
    for (int m = 0; m < 2; ++m)
#pragma unroll
        for (int nf = 0; nf < 4; ++nf) {
            accg[m][nf] = (f32x4){0,0,0,0};
            accu[m][nf] = (f32x4){0,0,0,0};
        }

    bf16x8 a[2][4];   // ping-pong A sets (indices static under full unroll)

    // prologue: stage slabs 0,1; load A(0)
    gl_lds16(gsrc,        &Bg[0][w * 1024]);
    gl_lds16(gsrc + 512,  &Bg[0][w * 1024 + 512]);
    gl_lds16(usrc,        &Bu[0][w * 1024]);
    gl_lds16(usrc + 512,  &Bu[0][w * 1024 + 512]);
    gl_lds16(gsrc + 4096,       &Bg[1][w * 1024]);
    gl_lds16(gsrc + 4096 + 512, &Bg[1][w * 1024 + 512]);
    gl_lds16(usrc + 4096,       &Bu[1][w * 1024]);
    gl_lds16(usrc + 4096 + 512, &Bu[1][w * 1024 + 512]);
    a[0][0] = *(const bf16x8*)(a0p);
    a[0][1] = *(const bf16x8*)(a0p + 32);
    a[0][2] = *(const bf16x8*)(a1p);
    a[0][3] = *(const bf16x8*)(a1p + 32);
    PIPE_BARRIER(8)     // drains stage(0); stage(1)+A(0) stay in flight

#pragma unroll
    for (int it = 0; it < 16; ++it) {
        if (it + 2 < 16) {                       // stage slab it+2 into buf (it+2)%3
            const short* gs = gsrc + (size_t)(it + 2) * 4096;
            const short* us = usrc + (size_t)(it + 2) * 4096;
            short* bg = &Bg[(it + 2) % 3][w * 1024];
            short* bu = &Bu[(it + 2) % 3][w * 1024];
            gl_lds16(gs,       bg);
            gl_lds16(gs + 512, bg + 512);
            gl_lds16(us,       bu);
            gl_lds16(us + 512, bu + 512);
        }
        if (it + 1 < 16) {                       // load A(it+1) into other set
            int kn = (it + 1) * 64;
            a[(it + 1) & 1][0] = *(const bf16x8*)(a0p + kn);
            a[(it + 1) & 1][1] = *(const bf16x8*)(a0p + kn + 32);
            a[(it + 1) & 1][2] = *(const bf16x8*)(a1p + kn);
            a[(it + 1) & 1][3] = *(const bf16x8*)(a1p + kn + 32);
        }

        const short* Bgb = &Bg[it % 3][0];
        const short* Bub = &Bu[it % 3][0];
        bf16x8 a00 = a[it & 1][0], a01 = a[it & 1][1];
        bf16x8 a10 = a[it & 1][2], a11 = a[it & 1][3];
#pragma unroll
        for (int nf = 0; nf < 4; ++nf) {
            bf16x8 bg0 = *(const bf16x8*)&Bgb[boff0[nf]];
            bf16x8 bg1 = *(const bf16x8*)&Bgb[boff1[nf]];
            bf16x8 bu0 = *(const bf16x8*)&Bub[boff0[nf]];
            bf16x8 bu1 = *(const bf16x8*)&Bub[boff1[nf]];
            accg[0][nf] = __builtin_amdgcn_mfma_f32_16x16x32_bf16(a00, bg0, accg[0][nf], 0, 0, 0);
            accg[0][nf] = __builtin_amdgcn_mfma_f32_16x16x32_bf16(a01, bg1, accg[0][nf], 0, 0, 0);
            accg[1][nf] = __builtin_amdgcn_mfma_f32_16x16x32_bf16(a10, bg0, accg[1][nf], 0, 0, 0);
            accg[1][nf] = __builtin_amdgcn_mfma_f32_16x16x32_bf16(a11, bg1, accg[1][nf], 0, 0, 0);
            accu[0][nf] = __builtin_amdgcn_mfma_f32_16x16x32_bf16(a00, bu0, accu[0][nf], 0, 0, 0);
            accu[0][nf] = __builtin_amdgcn_mfma_f32_16x16x32_bf16(a01, bu1, accu[0][nf], 0, 0, 0);
            accu[1][nf] = __builtin_amdgcn_mfma_f32_16x16x32_bf16(a10, bu0, accu[1][nf], 0, 0, 0);
            accu[1][nf] = __builtin_amdgcn_mfma_f32_16x16x32_bf16(a11, bu1, accu[1][nf], 0, 0, 0);
        }

        // it<14: 12 outstanding (stage(it+1)+stage(it+2)+A(it+1)); vmcnt(8)
        //        drains stage(it+1) before next iter reads it.
        // it==14: 8 outstanding (stage(15)+A(15)); vmcnt(4) drains stage(15).
        if (it < 14) {
            PIPE_BARRIER(8)
        } else if (it < 15) {
            PIPE_BARRIER(4)
        }
    }

    // epilogue: h = silu(gate) * up, masked rows
#pragma unroll
    for (int m = 0; m < 2; ++m) {
#pragma unroll
        for (int r = 0; r < 4; ++r) {
            int mr = p0 + w * 32 + m * 16 + quad * 4 + r;
            if (mr < pend) {
#pragma unroll
                for (int nf = 0; nf < 4; ++nf) {
                    float gv = accg[m][nf][r], uv = accu[m][nf][r];
                    float hv = (gv / (1.f + __expf(-gv))) * uv;
                    h[(size_t)mr * D_FF + nt * 64 + nf * 16 + col] = f2bf(hv);
                }
            }
        }
    }
}

// ---------------- GEMM2: out += h @ Wd (K-split x4), scatter via atomics ----------------
// grid (16 d-tiles, MAXT, KSPLIT), block 256. M=128 N=64 BK=64, 16 iters. 3-deep pipeline.

__launch_bounds__(256)
__global__ void moe_gemm2(const short* __restrict__ wdt, const short* __restrict__ h,
                          const int* __restrict__ tok_of_row, float* __restrict__ out,
                          const int* __restrict__ t_e, const int* __restrict__ t_p0,
                          const int* __restrict__ t_end, const int* __restrict__ ntp) {
    int ti = blockIdx.y;
    if (ti >= *ntp) return;
    int e = t_e[ti], p0 = t_p0[ti], pend = t_end[ti];
    int dt = blockIdx.x, z = blockIdx.z;

    __shared__ short Bd[3][4096];

    int tid = threadIdx.x;
    int lane = tid & 63, w = tid >> 6;
    int col = lane & 15, quad = lane >> 4;

    const short* dsrc = wdt + (((size_t)e * 16 + dt) * 64 + z * 16) * 4096 + w * 1024 + lane * 8;
    int Koff = z * (D_FF / KSPLIT);

    int row0 = p0 + w * 32 + col;  if (row0 > T_TOKENS - 1) row0 = T_TOKENS - 1;
    int row1 = row0 + 16;          if (row1 > T_TOKENS - 1) row1 = T_TOKENS - 1;
    const short* a0p = h + (size_t)row0 * D_FF + Koff + quad * 8;
    const short* a1p = h + (size_t)row1 * D_FF + Koff + quad * 8;

    int boff0[4], boff1[4];
#pragma unroll
    for (int nf = 0; nf < 4; ++nf) {
        int n = nf * 16 + col;
        boff0[nf] = n * 64 + ((quad ^ (n & 7)) * 8);
        boff1[nf] = n * 64 + (((quad + 4) ^ (n & 7)) * 8);
    }

    f32x4 acc[2][4];
#pragma unroll
    for (int m = 0; m < 2; ++m)
#pragma unroll
        for (int nf = 0; nf < 4; ++nf) acc[m][nf] = (f32x4){0,0,0,0};

    bf16x8 a[2][4];

    gl_lds16(dsrc,              &Bd[0][w * 1024]);
    gl_lds16(dsrc + 512,        &Bd[0][w * 1024 + 512]);
    gl_lds16(dsrc + 4096,       &Bd[1][w * 1024]);
    gl_lds16(dsrc + 4096 + 512, &Bd[1][w * 1024 + 512]);
    a[0][0] = *(const bf16x8*)(a0p);
    a[0][1] = *(const bf16x8*)(a0p + 32);
    a[0][2] = *(const bf16x8*)(a1p);
    a[0][3] = *(const bf16x8*)(a1p + 32);
    PIPE_BARRIER(6)     // drains stage(0); stage(1)+A(0) stay in flight

#pragma unroll
    for (int it = 0; it < 16; ++it) {
        if (it + 2 < 16) {
            const short* ds = dsrc + (size_t)(it + 2) * 4096;
            short* bd = &Bd[(it + 2) % 3][w * 1024];
            gl_lds16(ds,       bd);
            gl_lds16(ds + 512, bd + 512);
        }
        if (it + 1 < 16) {
            int kn = (it + 1) * 64;
            a[(it + 1) & 1][0] = *(const bf16x8*)(a0p + kn);
            a[(it + 1) & 1][1] = *(const bf16x8*)(a0p + kn + 32);
            a[(it + 1) & 1][2] = *(const bf16x8*)(a1p + kn);
            a[(it + 1) & 1][3] = *(const bf16x8*)(a1p + kn + 32);
        }

        const short* Bdb = &Bd[it % 3][0];
        bf16x8 a00 = a[it & 1][0], a01 = a[it & 1][1];
        bf16x8 a10 = a[it & 1][2], a11 = a[it & 1][3];
#pragma unroll
        for (int nf = 0; nf < 4; ++nf) {
            bf16x8 b0 = *(const bf16x8*)&Bdb[boff0[nf]];
            bf16x8 b1 = *(const bf16x8*)&Bdb[boff1[nf]];
            acc[0][nf] = __builtin_amdgcn_mfma_f32_16x16x32_bf16(a00, b0, acc[0][nf], 0, 0, 0);
            acc[0][nf] = __builtin_amdgcn_mfma_f32_16x16x32_bf16(a01, b1, acc[0][nf], 0, 0, 0);
            acc[1][nf] = __builtin_amdgcn_mfma_f32_16x16x32_bf16(a10, b0, acc[1][nf], 0, 0, 0);
            acc[1][nf] = __builtin_amdgcn_mfma_f32_16x16x32_bf16(a11, b1, acc[1][nf], 0, 0, 0);
        }

        // it<14: 8 outstanding; vmcnt(6) drains stage(it+1).
        // it==14: 6 outstanding (stage(15)2 + A(15)4); vmcnt(4) drains stage(15).
        if (it < 14) {
            PIPE_BARRIER(6)
        } else if (it < 15) {
            PIPE_BARRIER(4)
        }
    }

#pragma unroll
    for (int m = 0; m < 2; ++m) {
#pragma unroll
        for (int r = 0; r < 4; ++r) {
            int mr = p0 + w * 32 + m * 16 + quad * 4 + r;
            if (mr < pend) {
                int t = tok_of_row[mr];
#pragma unroll
                for (int nf = 0; nf < 4; ++nf)
                    atomicAdd(&out[(size_t)t * D_MODEL + dt * 64 + nf * 16 + col], acc[m][nf][r]);
            }
        }
    }
}

// ---------------- launch ----------------

extern "C" void kernel_launch(void* const* d_in, const int* in_sizes, int n_in,
                              void* d_out, int out_size, void* d_ws, size_t ws_size,
                              hipStream_t stream) {
    (void)in_sizes; (void)n_in; (void)out_size; (void)ws_size;
    const float* x   = (const float*)d_in[0];
    const int*   idx = (const int*)d_in[1];
    const float* wg  = (const float*)d_in[2];
    const float* wu  = (const float*)d_in[3];
    const float* wd  = (const float*)d_in[4];
    float* out = (float*)d_out;

    int* ws_i       = (int*)d_ws;
    int* cursor     = ws_i;            // 8   (memset to 0)
    int* offsets    = ws_i + 8;        // 9
    int* nt         = ws_i + 20;       // 1
    int* t_e        = ws_i + 32;       // 24
    int* t_p0       = ws_i + 64;       // 24
    int* t_end      = ws_i + 96;       // 24
    int* tok_of_row = ws_i + 256;      // 2048

    short* Xg  = (short*)((char*)d_ws + XG_OFF);
    short* h   = (short*)((char*)d_ws + H_OFF);
    short* WGt = (short*)((char*)d_ws + WG_OFF);
    short* WUt = (short*)((char*)d_ws + WU_OFF);
    short* WDt = (short*)((char*)d_ws + WD_OFF);

    hipMemsetAsync(d_ws, 0, 128, stream);
    hipMemsetAsync(out, 0, (size_t)T_TOKENS * D_MODEL * sizeof(float), stream);
    moe_route<<<dim3(1), 256, 0, stream>>>(idx, offsets, nt, t_e, t_p0, t_end);
    moe_gather<<<dim3(T_TOKENS), 256, 0, stream>>>(x, idx, offsets, cursor, tok_of_row, Xg);
    moe_repack<<<dim3(D_FF / 512, D_MODEL / 64, N_EXPERTS), 512, 0, stream>>>(wg, WGt, D_MODEL, D_FF);
    moe_repack<<<dim3(D_FF / 512, D_MODEL / 64, N_EXPERTS), 512, 0, stream>>>(wu, WUt, D_MODEL, D_FF);
    moe_repack<<<dim3(D_MODEL / 512, D_FF / 64, N_EXPERTS), 512, 0, stream>>>(wd, WDt, D_FF, D_MODEL);
    moe_gemm1<<<dim3(D_FF / 64, MAXT), 256, 0, stream>>>(WGt, WUt, Xg, h,
                                                         t_e, t_p0, t_end, nt);
    moe_gemm2<<<dim3(D_MODEL / 64, MAXT, KSPLIT), 256, 0, stream>>>(WDt, h, tok_of_row, out,
                                                                    t_e, t_p0, t_end, nt);
}